// Round 2
// baseline (2818.793 us; speedup 1.0000x reference)
//
#include <hip/hip_runtime.h>
#include <stdint.h>

typedef unsigned short u16;
typedef __bf16 bf16x8 __attribute__((ext_vector_type(8)));
typedef float floatx4 __attribute__((ext_vector_type(4)));

#define HIDDEN 2560
#define NHEADS 32
#define HD 80
#define SEQ 2048
#define BATCH 2
#define MROWS (BATCH*SEQ)
#define KT 64

__device__ __forceinline__ float bf2f(uint32_t bits) {
    return __uint_as_float(bits << 16);
}
__device__ __forceinline__ u16 f2bf_bits(float f) {
    uint32_t x = __float_as_uint(f);
    uint32_t r = (x + 0x7fffu + ((x >> 16) & 1u)) >> 16;  // RTNE
    return (u16)r;
}

// ---------------- transpose: out[n][k] = in[k][n], 2560x2560 fp32 ----------------
__global__ __launch_bounds__(256) void transpose_w(const float* __restrict__ in,
                                                   float* __restrict__ out) {
    __shared__ float t[64][65];
    int k0 = blockIdx.x * 64;
    int n0 = blockIdx.y * 64;
    int tid = threadIdx.x;
    int rr = tid >> 4;           // 0..15
    int c4 = (tid & 15) * 4;     // 0..60
#pragma unroll
    for (int it = 0; it < 4; it++) {
        int row = it * 16 + rr;
        float4 v = *(const float4*)&in[(size_t)(k0 + row) * HIDDEN + n0 + c4];
        t[row][c4 + 0] = v.x; t[row][c4 + 1] = v.y;
        t[row][c4 + 2] = v.z; t[row][c4 + 3] = v.w;
    }
    __syncthreads();
#pragma unroll
    for (int it = 0; it < 4; it++) {
        int row = it * 16 + rr;
        float4 v;
        v.x = t[c4 + 0][row]; v.y = t[c4 + 1][row];
        v.z = t[c4 + 2][row]; v.w = t[c4 + 3][row];
        *(float4*)&out[(size_t)(n0 + row) * HIDDEN + k0 + c4] = v;
    }
}

// ------- GEMM: C[M][N] = A[M][K] * Bt[N][K]^T, fp32 in/out, split-bf16 MFMA ------
// 128x128 tile, BK=32, 4 waves, each wave 4x4 mfma_f32_16x16x32_bf16, 3 passes
// (hi*hi + hi*lo + lo*hi) -> ~2^-17 relative error vs fp32.
__global__ __launch_bounds__(256) void gemm_bt(const float* __restrict__ A,
                                               const float* __restrict__ Bt,
                                               float* __restrict__ C) {
    __shared__ u16 lAh[128 * 40];   // pitch 40 (2-way bank aliasing only)
    __shared__ u16 lAl[128 * 40];
    __shared__ u16 lBh[128 * 40];
    __shared__ u16 lBl[128 * 40];
    const int K = HIDDEN;
    int tid  = threadIdx.x;
    int lane = tid & 63;
    int wave = tid >> 6;
    int wr = wave >> 1, wc = wave & 1;
    int m0 = blockIdx.y * 128, n0 = blockIdx.x * 128;
    int lr = lane & 15, lq = lane >> 4;
    int arow = tid >> 1;             // 0..127
    int ak16 = (tid & 1) << 4;       // 0 or 16

    floatx4 acc[4][4];
#pragma unroll
    for (int i = 0; i < 4; i++)
#pragma unroll
        for (int j = 0; j < 4; j++)
            acc[i][j] = (floatx4){0.f, 0.f, 0.f, 0.f};

    for (int k0 = 0; k0 < K; k0 += 32) {
        // stage A and B: each thread 16 floats of each, split into hi/lo bf16
        {
            const float* ap = &A[(size_t)(m0 + arow) * K + k0 + ak16];
            const float* bp = &Bt[(size_t)(n0 + arow) * K + k0 + ak16];
            u16 h[16], l[16];
#pragma unroll
            for (int c = 0; c < 4; c++) {
                float4 v = *(const float4*)(ap + c * 4);
                float f[4] = {v.x, v.y, v.z, v.w};
#pragma unroll
                for (int j = 0; j < 4; j++) {
                    u16 hb = f2bf_bits(f[j]);
                    h[c * 4 + j] = hb;
                    l[c * 4 + j] = f2bf_bits(f[j] - bf2f(hb));
                }
            }
            *(int4*)&lAh[arow * 40 + ak16]     = *(int4*)&h[0];
            *(int4*)&lAh[arow * 40 + ak16 + 8] = *(int4*)&h[8];
            *(int4*)&lAl[arow * 40 + ak16]     = *(int4*)&l[0];
            *(int4*)&lAl[arow * 40 + ak16 + 8] = *(int4*)&l[8];
#pragma unroll
            for (int c = 0; c < 4; c++) {
                float4 v = *(const float4*)(bp + c * 4);
                float f[4] = {v.x, v.y, v.z, v.w};
#pragma unroll
                for (int j = 0; j < 4; j++) {
                    u16 hb = f2bf_bits(f[j]);
                    h[c * 4 + j] = hb;
                    l[c * 4 + j] = f2bf_bits(f[j] - bf2f(hb));
                }
            }
            *(int4*)&lBh[arow * 40 + ak16]     = *(int4*)&h[0];
            *(int4*)&lBh[arow * 40 + ak16 + 8] = *(int4*)&h[8];
            *(int4*)&lBl[arow * 40 + ak16]     = *(int4*)&l[0];
            *(int4*)&lBl[arow * 40 + ak16 + 8] = *(int4*)&l[8];
        }
        __syncthreads();
        bf16x8 ah[4], al[4], bh[4], bl[4];
#pragma unroll
        for (int i = 0; i < 4; i++) {
            int ra = (wr * 64 + i * 16 + lr) * 40 + lq * 8;
            int rb = (wc * 64 + i * 16 + lr) * 40 + lq * 8;
            ah[i] = *(const bf16x8*)&lAh[ra];
            al[i] = *(const bf16x8*)&lAl[ra];
            bh[i] = *(const bf16x8*)&lBh[rb];
            bl[i] = *(const bf16x8*)&lBl[rb];
        }
#pragma unroll
        for (int i = 0; i < 4; i++)
#pragma unroll
            for (int j = 0; j < 4; j++) {
                acc[i][j] = __builtin_amdgcn_mfma_f32_16x16x32_bf16(ah[i], bh[j], acc[i][j], 0, 0, 0);
                acc[i][j] = __builtin_amdgcn_mfma_f32_16x16x32_bf16(ah[i], bl[j], acc[i][j], 0, 0, 0);
                acc[i][j] = __builtin_amdgcn_mfma_f32_16x16x32_bf16(al[i], bh[j], acc[i][j], 0, 0, 0);
            }
        __syncthreads();
    }
    // C/D layout (m89-verified): row=(lane>>4)*4+reg, col=lane&15
#pragma unroll
    for (int i = 0; i < 4; i++) {
        int rowb = m0 + wr * 64 + i * 16 + lq * 4;
#pragma unroll
        for (int j = 0; j < 4; j++) {
            int col = n0 + wc * 64 + j * 16 + lr;
#pragma unroll
            for (int r = 0; r < 4; r++)
                C[(size_t)(rowb + r) * HIDDEN + col] = acc[i][j][r];
        }
    }
}

// ---------------- RoPE (ROT=20 -> 10 pairs) on Q and K, in place, fp32 -----------
__global__ __launch_bounds__(256) void rope_k(float* __restrict__ Qb, float* __restrict__ Kb,
                                              const int* __restrict__ pos_ids) {
    int idx = blockIdx.x * 256 + threadIdx.x;   // MROWS*NHEADS threads
    int row = idx >> 5;
    int h   = idx & 31;
    float pos = (float)pos_ids[row];
    size_t base = (size_t)row * HIDDEN + h * HD;
    float* q = Qb + base;
    float* k = Kb + base;
#pragma unroll
    for (int i = 0; i < 10; i++) {
        // inv_freq[i] = 10000^(-i/10) = 2^(-i*log2(10000)/10)
        float freq = pos * exp2f(-1.3287712379549449f * (float)i);
        float sn, cs;
        sincosf(freq, &sn, &cs);
        float q1 = q[i], q2 = q[i + 10];
        q[i]      = q1 * cs - q2 * sn;
        q[i + 10] = q2 * cs + q1 * sn;
        float k1 = k[i], k2 = k[i + 10];
        k[i]      = k1 * cs - k2 * sn;
        k[i + 10] = k2 * cs + k1 * sn;
    }
}

// ---------------- flash attention (scalar, fp32 LDS tiles) -----------------------
// block = 256 consecutive queries of one (b,h); K/V staged per 64-key tile.
__global__ __launch_bounds__(256) void attn_k(const float* __restrict__ Qb,
                                              const float* __restrict__ Kb,
                                              const float* __restrict__ Vb,
                                              float* __restrict__ Ob) {
    __shared__ float sK[KT][HD];
    __shared__ float sV[KT][HD];
    int bh = blockIdx.x;            // 0..63
    int qc = blockIdx.y;            // 0..7
    int b = bh >> 5, h = bh & 31;
    int tid = threadIdx.x;
    int q = qc * 256 + tid;
    size_t headbase = (size_t)b * SEQ * HIDDEN + (size_t)h * HD;

    float qv[HD];
    {
        const float4* qp = (const float4*)(Qb + headbase + (size_t)q * HIDDEN);
#pragma unroll
        for (int c = 0; c < 20; c++) {
            float4 v = qp[c];
            qv[c * 4 + 0] = v.x * 0.11180339887498949f;
            qv[c * 4 + 1] = v.y * 0.11180339887498949f;
            qv[c * 4 + 2] = v.z * 0.11180339887498949f;
            qv[c * 4 + 3] = v.w * 0.11180339887498949f;
        }
    }
    float m = -3.0e38f, l = 0.f;
    float acc[HD];
#pragma unroll
    for (int d = 0; d < HD; d++) acc[d] = 0.f;

    int ntiles = qc * 4 + 4;        // covers keys 0 .. qc*256+255
    for (int t = 0; t < ntiles; t++) {
        int k0 = t * KT;
        // stage K and V tiles: 2*64*20 float4 copies / 256 threads = 10 each
        for (int idx = tid; idx < KT * 20 * 2; idx += 256) {
            int half = (idx >= KT * 20) ? 1 : 0;
            int e = half ? idx - KT * 20 : idx;
            int j = e / 20, c = e % 20;
            const float4* src = (const float4*)((half ? Vb : Kb) + headbase +
                                                (size_t)(k0 + j) * HIDDEN + c * 4);
            float4 v = *src;
            *(float4*)((half ? &sV[0][0] : &sK[0][0]) + j * HD + c * 4) = v;
        }
        __syncthreads();
        int jmax = q - k0; if (jmax > KT - 1) jmax = KT - 1;
        for (int j0 = 0; j0 <= jmax; j0 += 8) {
            float sv[8];
            float tm = -3.0e38f;
#pragma unroll
            for (int jj = 0; jj < 8; jj++) {
                const float* kr = &sK[j0 + jj][0];
                float d = 0.f;
#pragma unroll
                for (int dd = 0; dd < HD; dd++) d = fmaf(qv[dd], kr[dd], d);
                sv[jj] = (j0 + jj <= jmax) ? d : -3.0e38f;
                tm = fmaxf(tm, sv[jj]);
            }
            if (tm > m) {
                float alpha = __expf(m - tm);
                m = tm;
                l *= alpha;
#pragma unroll
                for (int dd = 0; dd < HD; dd++) acc[dd] *= alpha;
            }
#pragma unroll
            for (int jj = 0; jj < 8; jj++) {
                float p = __expf(sv[jj] - m);
                l += p;
                const float* vr = &sV[j0 + jj][0];
#pragma unroll
                for (int dd = 0; dd < HD; dd++) acc[dd] = fmaf(p, vr[dd], acc[dd]);
            }
        }
        __syncthreads();
    }
    float inv = 1.f / l;
    float* op = Ob + headbase + (size_t)q * HIDDEN;
#pragma unroll
    for (int c = 0; c < 20; c++) {
        float4 v;
        v.x = acc[c * 4 + 0] * inv;
        v.y = acc[c * 4 + 1] * inv;
        v.z = acc[c * 4 + 2] * inv;
        v.w = acc[c * 4 + 3] * inv;
        *(float4*)(op + c * 4) = v;
    }
}

extern "C" void kernel_launch(void* const* d_in, const int* in_sizes, int n_in,
                              void* d_out, int out_size, void* d_ws, size_t ws_size,
                              hipStream_t stream) {
    const float* hidden = (const float*)d_in[0];
    // d_in[1] = attention_mask (all ones; unused by the reference math)
    const int* pos    = (const int*)d_in[2];
    const float* Wq   = (const float*)d_in[3];
    const float* Wk   = (const float*)d_in[4];
    const float* Wv   = (const float*)d_in[5];
    const float* Wo   = (const float*)d_in[6];

    float* ws = (float*)d_ws;
    const size_t NQ = (size_t)MROWS * HIDDEN;          // 10,485,760 elems
    float* Qb = ws;
    float* Kb = ws + NQ;
    float* Vb = ws + 2 * NQ;
    float* Ob = ws + 3 * NQ;
    float* WT = ws + 4 * NQ;                           // 2560*2560 elems
    // total ws use: (4*NQ + 2560^2) * 4 B ~= 185 MB

    dim3 blk(256);
    dim3 tgrid(HIDDEN / 64, HIDDEN / 64);              // 40x40
    dim3 ggrid(HIDDEN / 128, MROWS / 128);             // 20x32

    transpose_w<<<tgrid, blk, 0, stream>>>(Wq, WT);
    gemm_bt<<<ggrid, blk, 0, stream>>>(hidden, WT, Qb);
    transpose_w<<<tgrid, blk, 0, stream>>>(Wk, WT);
    gemm_bt<<<ggrid, blk, 0, stream>>>(hidden, WT, Kb);
    transpose_w<<<tgrid, blk, 0, stream>>>(Wv, WT);
    gemm_bt<<<ggrid, blk, 0, stream>>>(hidden, WT, Vb);
    rope_k<<<dim3(MROWS * NHEADS / 256), blk, 0, stream>>>(Qb, Kb, pos);
    attn_k<<<dim3(BATCH * NHEADS, SEQ / 256), blk, 0, stream>>>(Qb, Kb, Vb, Ob);
    transpose_w<<<tgrid, blk, 0, stream>>>(Wo, WT);
    gemm_bt<<<ggrid, blk, 0, stream>>>(Ob, WT, (float*)d_out);
}

// Round 3
// 2497.396 us; speedup vs baseline: 1.1287x; 1.1287x over previous
//
#include <hip/hip_runtime.h>
#include <stdint.h>

typedef unsigned short u16;
typedef __bf16 bf16x8 __attribute__((ext_vector_type(8)));
typedef float floatx4 __attribute__((ext_vector_type(4)));

#define HIDDEN 2560
#define NHEADS 32
#define HD 80
#define SEQ 2048
#define BATCH 2
#define MROWS (BATCH*SEQ)
#define KT2 32

__device__ __forceinline__ float bf2f(uint32_t bits) {
    return __uint_as_float(bits << 16);
}
__device__ __forceinline__ u16 f2bf_bits(float f) {
    uint32_t x = __float_as_uint(f);
    uint32_t r = (x + 0x7fffu + ((x >> 16) & 1u)) >> 16;  // RTNE
    return (u16)r;
}

// ---------------- split fp32 -> bf16 hi/lo, elementwise ---------------------------
__global__ __launch_bounds__(256) void split_x(const float* __restrict__ in,
                                               u16* __restrict__ hi,
                                               u16* __restrict__ lo) {
    size_t i4 = (size_t)blockIdx.x * 256 + threadIdx.x;
    float4 v = ((const float4*)in)[i4];
    float f[4] = {v.x, v.y, v.z, v.w};
    u16 h[4], l[4];
#pragma unroll
    for (int j = 0; j < 4; j++) {
        h[j] = f2bf_bits(f[j]);
        l[j] = f2bf_bits(f[j] - bf2f(h[j]));
    }
    ((uint2*)hi)[i4] = *(uint2*)h;
    ((uint2*)lo)[i4] = *(uint2*)l;
}

// ------------- transpose + split: W[k][n] fp32 -> WT hi/lo bf16 [n][k] ------------
__global__ __launch_bounds__(256) void split_wt(const float* __restrict__ in,
                                                u16* __restrict__ outh,
                                                u16* __restrict__ outl) {
    __shared__ float t[64][65];
    int k0 = blockIdx.x * 64;
    int n0 = blockIdx.y * 64;
    int tid = threadIdx.x;
    int rr = tid >> 4;           // 0..15
    int c4 = (tid & 15) * 4;     // 0..60
#pragma unroll
    for (int it = 0; it < 4; it++) {
        int row = it * 16 + rr;
        float4 v = *(const float4*)&in[(size_t)(k0 + row) * HIDDEN + n0 + c4];
        t[row][c4 + 0] = v.x; t[row][c4 + 1] = v.y;
        t[row][c4 + 2] = v.z; t[row][c4 + 3] = v.w;
    }
    __syncthreads();
#pragma unroll
    for (int it = 0; it < 4; it++) {
        int row = it * 16 + rr;
        float f[4] = { t[c4 + 0][row], t[c4 + 1][row], t[c4 + 2][row], t[c4 + 3][row] };
        u16 h[4], l[4];
#pragma unroll
        for (int j = 0; j < 4; j++) {
            h[j] = f2bf_bits(f[j]);
            l[j] = f2bf_bits(f[j] - bf2f(h[j]));
        }
        size_t o = (size_t)(n0 + row) * HIDDEN + k0 + c4;
        *(uint2*)&outh[o] = *(uint2*)h;
        *(uint2*)&outl[o] = *(uint2*)l;
    }
}

// ------- GEMM: C[M][N] = A[M][K] * Bt[N][K]^T, pre-split bf16 in, fp32 out --------
// 128x128 tile, BK=32, 4 waves, 4x4 mfma_f32_16x16x32_bf16, 3 passes
// (hi*hi + hi*lo + lo*hi) -> ~2^-17 relative error vs fp32.
__global__ __launch_bounds__(256) void gemm_bt2(const u16* __restrict__ Ah,
                                                const u16* __restrict__ Al,
                                                const u16* __restrict__ Bh,
                                                const u16* __restrict__ Bl,
                                                float* __restrict__ C) {
    __shared__ u16 lAh[128 * 40];   // pitch 40 (2-way bank aliasing only)
    __shared__ u16 lAl[128 * 40];
    __shared__ u16 lBh[128 * 40];
    __shared__ u16 lBl[128 * 40];
    const int K = HIDDEN;
    int tid  = threadIdx.x;
    int lane = tid & 63;
    int wave = tid >> 6;
    int wr = wave >> 1, wc = wave & 1;
    int m0 = blockIdx.y * 128, n0 = blockIdx.x * 128;
    int lr = lane & 15, lq = lane >> 4;
    int arow = tid >> 1;             // 0..127
    int ak16 = (tid & 1) << 4;       // 0 or 16

    floatx4 acc[4][4];
#pragma unroll
    for (int i = 0; i < 4; i++)
#pragma unroll
        for (int j = 0; j < 4; j++)
            acc[i][j] = (floatx4){0.f, 0.f, 0.f, 0.f};

    for (int k0 = 0; k0 < K; k0 += 32) {
        size_t aoff = (size_t)(m0 + arow) * K + k0 + ak16;
        size_t boff = (size_t)(n0 + arow) * K + k0 + ak16;
        int ldst = arow * 40 + ak16;
        *(int4*)&lAh[ldst]     = *(const int4*)&Ah[aoff];
        *(int4*)&lAh[ldst + 8] = *(const int4*)&Ah[aoff + 8];
        *(int4*)&lAl[ldst]     = *(const int4*)&Al[aoff];
        *(int4*)&lAl[ldst + 8] = *(const int4*)&Al[aoff + 8];
        *(int4*)&lBh[ldst]     = *(const int4*)&Bh[boff];
        *(int4*)&lBh[ldst + 8] = *(const int4*)&Bh[boff + 8];
        *(int4*)&lBl[ldst]     = *(const int4*)&Bl[boff];
        *(int4*)&lBl[ldst + 8] = *(const int4*)&Bl[boff + 8];
        __syncthreads();
        bf16x8 ah[4], al[4], bh[4], bl[4];
#pragma unroll
        for (int i = 0; i < 4; i++) {
            int ra = (wr * 64 + i * 16 + lr) * 40 + lq * 8;
            int rb = (wc * 64 + i * 16 + lr) * 40 + lq * 8;
            ah[i] = *(const bf16x8*)&lAh[ra];
            al[i] = *(const bf16x8*)&lAl[ra];
            bh[i] = *(const bf16x8*)&lBh[rb];
            bl[i] = *(const bf16x8*)&lBl[rb];
        }
#pragma unroll
        for (int i = 0; i < 4; i++)
#pragma unroll
            for (int j = 0; j < 4; j++) {
                acc[i][j] = __builtin_amdgcn_mfma_f32_16x16x32_bf16(ah[i], bh[j], acc[i][j], 0, 0, 0);
                acc[i][j] = __builtin_amdgcn_mfma_f32_16x16x32_bf16(ah[i], bl[j], acc[i][j], 0, 0, 0);
                acc[i][j] = __builtin_amdgcn_mfma_f32_16x16x32_bf16(al[i], bh[j], acc[i][j], 0, 0, 0);
            }
        __syncthreads();
    }
    // C/D layout (m89-verified): row=(lane>>4)*4+reg, col=lane&15
#pragma unroll
    for (int i = 0; i < 4; i++) {
        int rowb = m0 + wr * 64 + i * 16 + lq * 4;
#pragma unroll
        for (int j = 0; j < 4; j++) {
            int col = n0 + wc * 64 + j * 16 + lr;
#pragma unroll
            for (int r = 0; r < 4; r++)
                C[(size_t)(rowb + r) * HIDDEN + col] = acc[i][j][r];
        }
    }
}

// ---------------- RoPE (ROT=20 -> 10 pairs) on Q and K, in place, fp32 -----------
__global__ __launch_bounds__(256) void rope_k(float* __restrict__ Qb, float* __restrict__ Kb,
                                              const int* __restrict__ pos_ids) {
    int idx = blockIdx.x * 256 + threadIdx.x;   // MROWS*NHEADS threads
    int row = idx >> 5;
    int h   = idx & 31;
    float pos = (float)pos_ids[row];
    size_t base = (size_t)row * HIDDEN + h * HD;
    float* q = Qb + base;
    float* k = Kb + base;
#pragma unroll
    for (int i = 0; i < 10; i++) {
        float freq = pos * exp2f(-1.3287712379549449f * (float)i);
        float sn, cs;
        sincosf(freq, &sn, &cs);
        float q1 = q[i], q2 = q[i + 10];
        q[i]      = q1 * cs - q2 * sn;
        q[i + 10] = q2 * cs + q1 * sn;
        float k1 = k[i], k2 = k[i + 10];
        k[i]      = k1 * cs - k2 * sn;
        k[i + 10] = k2 * cs + k1 * sn;
    }
}

// ---------------- flash attention, 2-way key-split per query ---------------------
// block = 128 queries of one (b,h); tid<128 -> first half of keys, tid>=128 ->
// second half; online-softmax states merged through LDS at the end.
// Writes O directly as split-bf16 (hi/lo).
__global__ __launch_bounds__(256) void attn_k2(const float* __restrict__ Qb,
                                               const float* __restrict__ Kb,
                                               const float* __restrict__ Vb,
                                               u16* __restrict__ Oh,
                                               u16* __restrict__ Ol) {
    __shared__ float smem[2 * KT2 * HD * 2];   // 10240 floats = 40 KB
    // layout: K tiles at [half*2560 + j*80 + d], V tiles at [5120 + half*2560 + ...]
    int bh = blockIdx.x;                        // 0..63
    int qc = (gridDim.y - 1) - blockIdx.y;      // long blocks first
    int b = bh >> 5, h = bh & 31;
    int tid = threadIdx.x;
    int qi = tid & 127, half = tid >> 7;
    int q = qc * 128 + qi;
    int base1 = 64 * (qc + 1);                  // start of half-1 key range
    size_t headbase = (size_t)b * SEQ * HIDDEN + (size_t)h * HD;

    float qv[HD];
    {
        const float4* qp = (const float4*)(Qb + headbase + (size_t)q * HIDDEN);
#pragma unroll
        for (int c = 0; c < 20; c++) {
            float4 v = qp[c];
            qv[c * 4 + 0] = v.x * 0.11180339887498949f;
            qv[c * 4 + 1] = v.y * 0.11180339887498949f;
            qv[c * 4 + 2] = v.z * 0.11180339887498949f;
            qv[c * 4 + 3] = v.w * 0.11180339887498949f;
        }
    }
    float m = -3.0e38f, l = 0.f;
    float acc[HD];
#pragma unroll
    for (int d = 0; d < HD; d++) acc[d] = 0.f;

    int myk0base = half ? base1 : 0;
    int nt = 2 * (qc + 1);
    for (int t = 0; t < nt; t++) {
        // stage 4 tiles (K0,K1,V0,V1), each 32x80 fp32: 2560 float4 / 256 thr
#pragma unroll
        for (int it = 0; it < 10; it++) {
            int idx = tid + it * 256;
            int tile = idx / 640;               // 0:K0 1:K1 2:V0 3:V1
            int e = idx - tile * 640;
            int j = e / 20, c = e - j * 20;
            int kk = ((tile & 1) ? base1 : 0) + t * 32 + j;
            const float* srcb = (tile >= 2) ? Vb : Kb;
            float4 v = *(const float4*)(srcb + headbase + (size_t)kk * HIDDEN + c * 4);
            *(float4*)(smem + (tile >= 2 ? 5120 : 0) + (tile & 1) * 2560 + j * 80 + c * 4) = v;
        }
        __syncthreads();
        int k0h = myk0base + t * 32;
        int jmax = q - k0h; if (jmax > KT2 - 1) jmax = KT2 - 1;
        const float* kb = smem + half * 2560;
        const float* vb = smem + 5120 + half * 2560;
        for (int j0 = 0; j0 <= jmax; j0 += 8) {
            float sv[8];
            float tm = -3.0e38f;
#pragma unroll
            for (int jj = 0; jj < 8; jj++) {
                const float* kr = kb + (j0 + jj) * 80;
                float d = 0.f;
#pragma unroll
                for (int dd = 0; dd < HD; dd++) d = fmaf(qv[dd], kr[dd], d);
                sv[jj] = (j0 + jj <= jmax) ? d : -3.0e38f;
                tm = fmaxf(tm, sv[jj]);
            }
            if (tm > m) {
                float alpha = __expf(m - tm);
                m = tm;
                l *= alpha;
#pragma unroll
                for (int dd = 0; dd < HD; dd++) acc[dd] *= alpha;
            }
#pragma unroll
            for (int jj = 0; jj < 8; jj++) {
                float p = __expf(sv[jj] - m);
                l += p;
                const float* vr = vb + (j0 + jj) * 80;
#pragma unroll
                for (int dd = 0; dd < HD; dd++) acc[dd] = fmaf(p, vr[dd], acc[dd]);
            }
        }
        __syncthreads();
    }
    // ---- merge the two key-halves (half1 may be empty: m=-3e38, l=0, acc=0) ----
    if (half) { smem[qi * 2] = m; smem[qi * 2 + 1] = l; }
    __syncthreads();
    float m1 = 0.f, l1 = 0.f;
    if (!half) { m1 = smem[qi * 2]; l1 = smem[qi * 2 + 1]; }
    __syncthreads();
    if (half) {
#pragma unroll
        for (int d = 0; d < HD; d++) smem[qi * 80 + d] = acc[d];
    }
    __syncthreads();
    if (!half) {
        float M = fmaxf(m, m1);
        float a0 = __expf(m - M), a1 = __expf(m1 - M);
        float L = a0 * l + a1 * l1;
        float inv = 1.f / L;
        u16* oph = Oh + headbase + (size_t)q * HIDDEN;
        u16* opl = Ol + headbase + (size_t)q * HIDDEN;
#pragma unroll
        for (int c = 0; c < 20; c++) {
            u16 hh[4], ll[4];
#pragma unroll
            for (int j = 0; j < 4; j++) {
                float o = (a0 * acc[c * 4 + j] + a1 * smem[qi * 80 + c * 4 + j]) * inv;
                hh[j] = f2bf_bits(o);
                ll[j] = f2bf_bits(o - bf2f(hh[j]));
            }
            *(uint2*)(oph + c * 4) = *(uint2*)hh;
            *(uint2*)(opl + c * 4) = *(uint2*)ll;
        }
    }
}

extern "C" void kernel_launch(void* const* d_in, const int* in_sizes, int n_in,
                              void* d_out, int out_size, void* d_ws, size_t ws_size,
                              hipStream_t stream) {
    const float* hidden = (const float*)d_in[0];
    // d_in[1] = attention_mask (all ones; unused by the reference math)
    const int* pos    = (const int*)d_in[2];
    const float* Wq   = (const float*)d_in[3];
    const float* Wk   = (const float*)d_in[4];
    const float* Wv   = (const float*)d_in[5];
    const float* Wo   = (const float*)d_in[6];

    const size_t NQ = (size_t)MROWS * HIDDEN;          // 10,485,760 elems
    float* ws = (float*)d_ws;
    float* Qb = ws;                                     // NQ fp32
    float* Kb = ws + NQ;                                // NQ fp32
    float* Vb = ws + 2 * NQ;                            // NQ fp32
    u16* Ah  = (u16*)(ws + 3 * NQ);                     // NQ u16
    u16* Al  = Ah + NQ;                                 // NQ u16
    u16* WTh = Al + NQ;                                 // 2560^2 u16
    u16* WTl = WTh + (size_t)HIDDEN * HIDDEN;           // 2560^2 u16
    // total: 3*NQ*4 + 2*NQ*2 + 2*2560^2*2 = 194 MB (same footprint as round 2)
    u16* Oh = Ah;   // hidden split no longer needed after the V GEMM
    u16* Ol = Al;

    dim3 blk(256);
    dim3 wgrid(HIDDEN / 64, HIDDEN / 64);              // 40x40
    dim3 ggrid(HIDDEN / 128, MROWS / 128);             // 20x32

    split_x<<<dim3(NQ / 4 / 256), blk, 0, stream>>>(hidden, Ah, Al);
    split_wt<<<wgrid, blk, 0, stream>>>(Wq, WTh, WTl);
    gemm_bt2<<<ggrid, blk, 0, stream>>>(Ah, Al, WTh, WTl, Qb);
    split_wt<<<wgrid, blk, 0, stream>>>(Wk, WTh, WTl);
    gemm_bt2<<<ggrid, blk, 0, stream>>>(Ah, Al, WTh, WTl, Kb);
    split_wt<<<wgrid, blk, 0, stream>>>(Wv, WTh, WTl);
    gemm_bt2<<<ggrid, blk, 0, stream>>>(Ah, Al, WTh, WTl, Vb);
    rope_k<<<dim3(MROWS * NHEADS / 256), blk, 0, stream>>>(Qb, Kb, pos);
    attn_k2<<<dim3(BATCH * NHEADS, SEQ / 128), blk, 0, stream>>>(Qb, Kb, Vb, Oh, Ol);
    split_wt<<<wgrid, blk, 0, stream>>>(Wo, WTh, WTl);
    gemm_bt2<<<ggrid, blk, 0, stream>>>(Oh, Ol, WTh, WTl, (float*)d_out);
}

// Round 4
// 1440.079 us; speedup vs baseline: 1.9574x; 1.7342x over previous
//
#include <hip/hip_runtime.h>
#include <stdint.h>

typedef unsigned short u16;
typedef __bf16 bf16x8 __attribute__((ext_vector_type(8)));
typedef float floatx4 __attribute__((ext_vector_type(4)));

#define HIDDEN 2560
#define NHEADS 32
#define HD 80
#define SEQ 2048
#define BATCH 2
#define MROWS (BATCH*SEQ)
#define QB 128

__device__ __forceinline__ float bf2f(uint32_t bits) {
    return __uint_as_float(bits << 16);
}
__device__ __forceinline__ u16 f2bf_bits(float f) {
    uint32_t x = __float_as_uint(f);
    uint32_t r = (x + 0x7fffu + ((x >> 16) & 1u)) >> 16;  // RTNE
    return (u16)r;
}
__device__ __forceinline__ floatx4 mk4(float x) {
    return (floatx4){x, x, x, x};
}
__device__ __forceinline__ floatx4 max4(floatx4 a, floatx4 b) {
    floatx4 r;
#pragma unroll
    for (int i = 0; i < 4; i++) r[i] = fmaxf(a[i], b[i]);
    return r;
}
__device__ __forceinline__ floatx4 exp4(floatx4 a) {
    floatx4 r;
#pragma unroll
    for (int i = 0; i < 4; i++) r[i] = __expf(a[i]);
    return r;
}
__device__ __forceinline__ floatx4 shfl_xor4(floatx4 v, int mask) {
    floatx4 r;
#pragma unroll
    for (int i = 0; i < 4; i++) r[i] = __shfl_xor(v[i], mask, 64);
    return r;
}

// ---------------- split fp32 -> bf16 hi/lo, elementwise ---------------------------
__global__ __launch_bounds__(256) void split_x(const float* __restrict__ in,
                                               u16* __restrict__ hi,
                                               u16* __restrict__ lo) {
    size_t i4 = (size_t)blockIdx.x * 256 + threadIdx.x;
    float4 v = ((const float4*)in)[i4];
    float f[4] = {v.x, v.y, v.z, v.w};
    u16 h[4], l[4];
#pragma unroll
    for (int j = 0; j < 4; j++) {
        h[j] = f2bf_bits(f[j]);
        l[j] = f2bf_bits(f[j] - bf2f(h[j]));
    }
    ((uint2*)hi)[i4] = *(uint2*)h;
    ((uint2*)lo)[i4] = *(uint2*)l;
}

// ------------- transpose + split: W[k][n] fp32 -> WT hi/lo bf16 [n][k] ------------
__global__ __launch_bounds__(256) void split_wt(const float* __restrict__ in,
                                                u16* __restrict__ outh,
                                                u16* __restrict__ outl) {
    __shared__ float t[64][65];
    int k0 = blockIdx.x * 64;
    int n0 = blockIdx.y * 64;
    int tid = threadIdx.x;
    int rr = tid >> 4;
    int c4 = (tid & 15) * 4;
#pragma unroll
    for (int it = 0; it < 4; it++) {
        int row = it * 16 + rr;
        float4 v = *(const float4*)&in[(size_t)(k0 + row) * HIDDEN + n0 + c4];
        t[row][c4 + 0] = v.x; t[row][c4 + 1] = v.y;
        t[row][c4 + 2] = v.z; t[row][c4 + 3] = v.w;
    }
    __syncthreads();
#pragma unroll
    for (int it = 0; it < 4; it++) {
        int row = it * 16 + rr;
        float f[4] = { t[c4 + 0][row], t[c4 + 1][row], t[c4 + 2][row], t[c4 + 3][row] };
        u16 h[4], l[4];
#pragma unroll
        for (int j = 0; j < 4; j++) {
            h[j] = f2bf_bits(f[j]);
            l[j] = f2bf_bits(f[j] - bf2f(h[j]));
        }
        size_t o = (size_t)(n0 + row) * HIDDEN + k0 + c4;
        *(uint2*)&outh[o] = *(uint2*)h;
        *(uint2*)&outl[o] = *(uint2*)l;
    }
}

// ------- GEMM: C[M][N] = A[M][K] * Bt[N][K]^T, pre-split bf16 in, fp32 out --------
__global__ __launch_bounds__(256) void gemm_bt2(const u16* __restrict__ Ah,
                                                const u16* __restrict__ Al,
                                                const u16* __restrict__ Bh,
                                                const u16* __restrict__ Bl,
                                                float* __restrict__ C) {
    __shared__ u16 lAh[128 * 40];
    __shared__ u16 lAl[128 * 40];
    __shared__ u16 lBh[128 * 40];
    __shared__ u16 lBl[128 * 40];
    const int K = HIDDEN;
    int tid  = threadIdx.x;
    int lane = tid & 63;
    int wave = tid >> 6;
    int wr = wave >> 1, wc = wave & 1;
    int m0 = blockIdx.y * 128, n0 = blockIdx.x * 128;
    int lr = lane & 15, lq = lane >> 4;
    int arow = tid >> 1;
    int ak16 = (tid & 1) << 4;

    floatx4 acc[4][4];
#pragma unroll
    for (int i = 0; i < 4; i++)
#pragma unroll
        for (int j = 0; j < 4; j++)
            acc[i][j] = mk4(0.f);

    for (int k0 = 0; k0 < K; k0 += 32) {
        size_t aoff = (size_t)(m0 + arow) * K + k0 + ak16;
        size_t boff = (size_t)(n0 + arow) * K + k0 + ak16;
        int ldst = arow * 40 + ak16;
        *(int4*)&lAh[ldst]     = *(const int4*)&Ah[aoff];
        *(int4*)&lAh[ldst + 8] = *(const int4*)&Ah[aoff + 8];
        *(int4*)&lAl[ldst]     = *(const int4*)&Al[aoff];
        *(int4*)&lAl[ldst + 8] = *(const int4*)&Al[aoff + 8];
        *(int4*)&lBh[ldst]     = *(const int4*)&Bh[boff];
        *(int4*)&lBh[ldst + 8] = *(const int4*)&Bh[boff + 8];
        *(int4*)&lBl[ldst]     = *(const int4*)&Bl[boff];
        *(int4*)&lBl[ldst + 8] = *(const int4*)&Bl[boff + 8];
        __syncthreads();
        bf16x8 ah[4], al[4], bh[4], bl[4];
#pragma unroll
        for (int i = 0; i < 4; i++) {
            int ra = (wr * 64 + i * 16 + lr) * 40 + lq * 8;
            int rb = (wc * 64 + i * 16 + lr) * 40 + lq * 8;
            ah[i] = *(const bf16x8*)&lAh[ra];
            al[i] = *(const bf16x8*)&lAl[ra];
            bh[i] = *(const bf16x8*)&lBh[rb];
            bl[i] = *(const bf16x8*)&lBl[rb];
        }
#pragma unroll
        for (int i = 0; i < 4; i++)
#pragma unroll
            for (int j = 0; j < 4; j++) {
                acc[i][j] = __builtin_amdgcn_mfma_f32_16x16x32_bf16(ah[i], bh[j], acc[i][j], 0, 0, 0);
                acc[i][j] = __builtin_amdgcn_mfma_f32_16x16x32_bf16(ah[i], bl[j], acc[i][j], 0, 0, 0);
                acc[i][j] = __builtin_amdgcn_mfma_f32_16x16x32_bf16(al[i], bh[j], acc[i][j], 0, 0, 0);
            }
        __syncthreads();
    }
#pragma unroll
    for (int i = 0; i < 4; i++) {
        int rowb = m0 + wr * 64 + i * 16 + lq * 4;
#pragma unroll
        for (int j = 0; j < 4; j++) {
            int col = n0 + wc * 64 + j * 16 + lr;
#pragma unroll
            for (int r = 0; r < 4; r++)
                C[(size_t)(rowb + r) * HIDDEN + col] = acc[i][j][r];
        }
    }
}

// ---------------- RoPE (ROT=20 -> 10 pairs) on Q and K, in place, fp32 -----------
__global__ __launch_bounds__(256) void rope_k(float* __restrict__ Qb, float* __restrict__ Kb,
                                              const int* __restrict__ pos_ids) {
    int idx = blockIdx.x * 256 + threadIdx.x;
    int row = idx >> 5;
    int h   = idx & 31;
    float pos = (float)pos_ids[row];
    size_t base = (size_t)row * HIDDEN + h * HD;
    float* q = Qb + base;
    float* k = Kb + base;
#pragma unroll
    for (int i = 0; i < 10; i++) {
        float freq = pos * exp2f(-1.3287712379549449f * (float)i);
        float sn, cs;
        sincosf(freq, &sn, &cs);
        float q1 = q[i], q2 = q[i + 10];
        q[i]      = q1 * cs - q2 * sn;
        q[i + 10] = q2 * cs + q1 * sn;
        float k1 = k[i], k2 = k[i + 10];
        k[i]      = k1 * cs - k2 * sn;
        k[i + 10] = k2 * cs + k1 * sn;
    }
}

// ---- V transpose+split: Vb fp32 [b*S+s][2560] -> Vth/Vtl u16 [bh][d(80)][s(2048)]
__global__ __launch_bounds__(256) void vtrans(const float* __restrict__ Vb,
                                              u16* __restrict__ Vth,
                                              u16* __restrict__ Vtl) {
    __shared__ float t[64][81];
    int bh = blockIdx.x; int b = bh >> 5, h = bh & 31;
    int s0 = blockIdx.y * 64;
    int tid = threadIdx.x;
    for (int idx = tid; idx < 64 * 20; idx += 256) {
        int s = idx / 20, c = idx % 20;
        float4 v = *(const float4*)&Vb[(size_t)(b * SEQ + s0 + s) * HIDDEN + h * HD + c * 4];
        t[s][c * 4 + 0] = v.x; t[s][c * 4 + 1] = v.y;
        t[s][c * 4 + 2] = v.z; t[s][c * 4 + 3] = v.w;
    }
    __syncthreads();
    for (int idx = tid; idx < 80 * 8; idx += 256) {
        int d = idx >> 3, sc = idx & 7;
        u16 hh[8], ll[8];
#pragma unroll
        for (int j = 0; j < 8; j++) {
            float f = t[sc * 8 + j][d];
            hh[j] = f2bf_bits(f);
            ll[j] = f2bf_bits(f - bf2f(hh[j]));
        }
        size_t o = ((size_t)bh * HD + d) * SEQ + s0 + sc * 8;
        *(int4*)&Vth[o] = *(int4*)hh;
        *(int4*)&Vtl[o] = *(int4*)ll;
    }
}

// ---------------- MFMA flash attention ------------------------------------------
// block: 128 queries of one (b,h); 4 waves x 32 queries (2 row-tiles of 16).
// K tiles: 32 keys, split bf16 hi/lo in LDS [key][96pad->pitch104].
// V tiles: from pre-transposed Vth/Vtl, LDS [dim(80)][key(32)] pitch 40.
// S = QK^T 3-pass split; P bf16 via wave-private LDS tile; PV 2-pass (Vh+Vl).
__global__ __launch_bounds__(256) void attn_mfma(const u16* __restrict__ Qh_,
                                                 const u16* __restrict__ Ql_,
                                                 const u16* __restrict__ Kh_,
                                                 const u16* __restrict__ Kl_,
                                                 const u16* __restrict__ Vth_,
                                                 const u16* __restrict__ Vtl_,
                                                 u16* __restrict__ Oh_,
                                                 u16* __restrict__ Ol_) {
    __shared__ u16 lds[15616];          // 31232 B
    u16* lKh = lds;                     // 32*104
    u16* lKl = lds + 3328;              // 32*104
    u16* lVh = lds + 6656;              // 80*40
    u16* lVl = lds + 9856;              // 80*40
    u16* lP  = lds + 13056;             // 4 waves * 16*40

    int tid = threadIdx.x;
    int lane = tid & 63, w = tid >> 6;
    int lr = lane & 15, lq = lane >> 4;
    int bh = blockIdx.x; int b = bh >> 5, h = bh & 31;
    int qblk = (gridDim.y - 1) - blockIdx.y;   // long blocks dispatched first
    int q0 = qblk * QB;
    size_t rowbase = (size_t)b * SEQ;
    size_t hoff = (size_t)h * HD;
    const float SC = 0.11180339887498949f;     // 1/sqrt(80)

    // ---- stage Q (two rounds of 64 rows through overlay region) -> A-frags ----
    bf16x8 qh[2][3], ql[2][3];
#pragma unroll
    for (int round = 0; round < 2; round++) {
        for (int idx = tid; idx < 1280; idx += 256) {
            int buf = idx >= 640; int e = idx - buf * 640;
            int r = e / 10, c = e % 10;
            const u16* src = (buf ? Ql_ : Qh_) +
                (rowbase + q0 + round * 64 + r) * HIDDEN + hoff + c * 8;
            *(int4*)&lds[buf * 6656 + r * 104 + c * 8] = *(const int4*)src;
        }
        {   // zero pad cols 80..95
            int idx = tid;
            if (idx < 256) {
                int buf = idx >= 128; int e = idx - buf * 128;
                int r = e >> 1, hf = e & 1;
                *(int4*)&lds[buf * 6656 + r * 104 + 80 + hf * 8] = make_int4(0, 0, 0, 0);
            }
        }
        __syncthreads();
        if ((w >> 1) == round) {
            int wl = w & 1;
#pragma unroll
            for (int rt = 0; rt < 2; rt++) {
                int lrow = wl * 32 + rt * 16 + lr;
#pragma unroll
                for (int c = 0; c < 3; c++) {
                    qh[rt][c] = *(const bf16x8*)&lds[lrow * 104 + c * 32 + lq * 8];
                    ql[rt][c] = *(const bf16x8*)&lds[6656 + lrow * 104 + c * 32 + lq * 8];
                }
            }
        }
        __syncthreads();
    }
    // zero K pad cols 80..95 (persists across tiles; staging only writes 0..79)
    if (tid < 128) {
        int buf = tid >= 64; int e = tid - buf * 64;
        int r = e >> 1, hf = e & 1;
        *(int4*)&lds[buf * 3328 + r * 104 + 80 + hf * 8] = make_int4(0, 0, 0, 0);
    }

    floatx4 acc[2][5];
    floatx4 mrow[2], lsum[2];
#pragma unroll
    for (int rt = 0; rt < 2; rt++) {
        mrow[rt] = mk4(-3.0e38f);
        lsum[rt] = mk4(0.f);
#pragma unroll
        for (int nt = 0; nt < 5; nt++) acc[rt][nt] = mk4(0.f);
    }

    int ntiles = 4 * qblk + 4;
    int qw0 = q0 + w * 32;
    u16* lPw = lP + w * 640;

    for (int t = 0; t < ntiles; t++) {
        int k0 = t * 32;
        // ---- stage K (hi/lo) and V (hi/lo): 1280 int4 / 256 threads ----
        for (int idx = tid; idx < 1280; idx += 256) {
            if (idx < 640) {
                int buf = idx >= 320; int e = idx - buf * 320;
                int r = e / 10, c = e % 10;
                const u16* src = (buf ? Kl_ : Kh_) +
                    (rowbase + k0 + r) * HIDDEN + hoff + c * 8;
                *(int4*)&lds[buf * 3328 + r * 104 + c * 8] = *(const int4*)src;
            } else {
                int e2 = idx - 640;
                int buf = e2 >= 320; int e = e2 - buf * 320;
                int d = e >> 2, kc = e & 3;
                const u16* src = (buf ? Vtl_ : Vth_) +
                    ((size_t)bh * HD + d) * SEQ + k0 + kc * 8;
                *(int4*)&lds[6656 + buf * 3200 + d * 40 + kc * 8] = *(const int4*)src;
            }
        }
        __syncthreads();
        if (k0 <= qw0 + 31) {
#pragma unroll
            for (int rt = 0; rt < 2; rt++) {
                int qrt0 = qw0 + rt * 16;
                if (k0 > qrt0 + 15) continue;
                // ---- S = Q K^T (two 16-key subtiles, 3-pass split) ----
                floatx4 s[2];
#pragma unroll
                for (int st = 0; st < 2; st++) {
                    floatx4 sv = mk4(0.f);
#pragma unroll
                    for (int c = 0; c < 3; c++) {
                        bf16x8 kh = *(const bf16x8*)&lKh[(st * 16 + lr) * 104 + c * 32 + lq * 8];
                        bf16x8 kl = *(const bf16x8*)&lKl[(st * 16 + lr) * 104 + c * 32 + lq * 8];
                        sv = __builtin_amdgcn_mfma_f32_16x16x32_bf16(qh[rt][c], kh, sv, 0, 0, 0);
                        sv = __builtin_amdgcn_mfma_f32_16x16x32_bf16(qh[rt][c], kl, sv, 0, 0, 0);
                        sv = __builtin_amdgcn_mfma_f32_16x16x32_bf16(ql[rt][c], kh, sv, 0, 0, 0);
                    }
                    s[st] = sv;
                }
                // ---- scale + causal mask ----
                int qg0 = qrt0 + lq * 4;      // row for reg r = qg0 + r
                int c0 = k0 + lr, c1 = c0 + 16;
#pragma unroll
                for (int r = 0; r < 4; r++) {
                    s[0][r] = (c0 <= qg0 + r) ? s[0][r] * SC : -3.0e38f;
                    s[1][r] = (c1 <= qg0 + r) ? s[1][r] * SC : -3.0e38f;
                }
                // ---- online softmax (16-lane row reductions) ----
                floatx4 rm = max4(s[0], s[1]);
#pragma unroll
                for (int off = 1; off < 16; off <<= 1) rm = max4(rm, shfl_xor4(rm, off));
                floatx4 mnew = max4(mrow[rt], rm);
                floatx4 alpha = exp4(mrow[rt] - mnew);
                mrow[rt] = mnew;
                floatx4 p0 = exp4(s[0] - mnew);
                floatx4 p1 = exp4(s[1] - mnew);
                floatx4 rs = p0 + p1;
#pragma unroll
                for (int off = 1; off < 16; off <<= 1) rs = rs + shfl_xor4(rs, off);
                lsum[rt] = lsum[rt] * alpha + rs;
#pragma unroll
                for (int nt = 0; nt < 5; nt++) acc[rt][nt] *= alpha;
                // ---- P (bf16) -> wave-private LDS, D-layout -> A-layout ----
#pragma unroll
                for (int r = 0; r < 4; r++) {
                    lPw[(lq * 4 + r) * 40 + lr]      = f2bf_bits(p0[r]);
                    lPw[(lq * 4 + r) * 40 + 16 + lr] = f2bf_bits(p1[r]);
                }
                __builtin_amdgcn_s_waitcnt(0xC07F);   // lgkmcnt(0) only (intra-wave LDS RAW)
                bf16x8 pa = *(const bf16x8*)&lPw[lr * 40 + lq * 8];
                // ---- O += P V ----
#pragma unroll
                for (int nt = 0; nt < 5; nt++) {
                    bf16x8 vh = *(const bf16x8*)&lVh[(nt * 16 + lr) * 40 + lq * 8];
                    bf16x8 vl = *(const bf16x8*)&lVl[(nt * 16 + lr) * 40 + lq * 8];
                    acc[rt][nt] = __builtin_amdgcn_mfma_f32_16x16x32_bf16(pa, vh, acc[rt][nt], 0, 0, 0);
                    acc[rt][nt] = __builtin_amdgcn_mfma_f32_16x16x32_bf16(pa, vl, acc[rt][nt], 0, 0, 0);
                }
            }
        }
        __syncthreads();
    }
    // ---- epilogue: O /= l, write split-bf16 ----
#pragma unroll
    for (int rt = 0; rt < 2; rt++) {
        floatx4 inv;
#pragma unroll
        for (int r = 0; r < 4; r++) inv[r] = 1.f / lsum[rt][r];
#pragma unroll
        for (int nt = 0; nt < 5; nt++) {
#pragma unroll
            for (int r = 0; r < 4; r++) {
                float o = acc[rt][nt][r] * inv[r];
                u16 hh = f2bf_bits(o);
                u16 ll = f2bf_bits(o - bf2f(hh));
                size_t row = rowbase + qw0 + rt * 16 + lq * 4 + r;
                Oh_[row * HIDDEN + hoff + nt * 16 + lr] = hh;
                Ol_[row * HIDDEN + hoff + nt * 16 + lr] = ll;
            }
        }
    }
}

extern "C" void kernel_launch(void* const* d_in, const int* in_sizes, int n_in,
                              void* d_out, int out_size, void* d_ws, size_t ws_size,
                              hipStream_t stream) {
    const float* hidden = (const float*)d_in[0];
    const int* pos    = (const int*)d_in[2];
    const float* Wq   = (const float*)d_in[3];
    const float* Wk   = (const float*)d_in[4];
    const float* Wv   = (const float*)d_in[5];
    const float* Wo   = (const float*)d_in[6];

    const size_t NQ = (size_t)MROWS * HIDDEN;          // 10,485,760 elems
    float* ws = (float*)d_ws;
    float* Qb = ws;                                     // [0, NQ) fp32
    float* Kb = ws + NQ;                                // [NQ, 2NQ) fp32
    float* Vb = ws + 2 * NQ;                            // [2NQ, 3NQ) fp32
    u16* Ah  = (u16*)(ws + 3 * NQ);                     // NQ u16
    u16* Al  = Ah + NQ;                                 // NQ u16
    u16* WTh = Al + NQ;                                 // 2560^2 u16
    u16* WTl = WTh + (size_t)HIDDEN * HIDDEN;           // 2560^2 u16
    // region reuse (194 MB total, same footprint as round 3):
    u16* Vth = Ah;                    // after QKV GEMMs, Ah/Al free
    u16* Vtl = Al;
    u16* Qh  = (u16*)Vb;              // after vtrans, Vb free
    u16* Ql  = Qh + NQ;
    u16* Kh  = (u16*)Qb;              // after Q split, Qb free
    u16* Kl  = Kh + NQ;
    u16* Oh  = (u16*)Kb;              // after K split, Kb free
    u16* Ol  = Oh + NQ;

    dim3 blk(256);
    dim3 wgrid(HIDDEN / 64, HIDDEN / 64);
    dim3 ggrid(HIDDEN / 128, MROWS / 128);

    split_x<<<dim3(NQ / 1024), blk, 0, stream>>>(hidden, Ah, Al);
    split_wt<<<wgrid, blk, 0, stream>>>(Wq, WTh, WTl);
    gemm_bt2<<<ggrid, blk, 0, stream>>>(Ah, Al, WTh, WTl, Qb);
    split_wt<<<wgrid, blk, 0, stream>>>(Wk, WTh, WTl);
    gemm_bt2<<<ggrid, blk, 0, stream>>>(Ah, Al, WTh, WTl, Kb);
    split_wt<<<wgrid, blk, 0, stream>>>(Wv, WTh, WTl);
    gemm_bt2<<<ggrid, blk, 0, stream>>>(Ah, Al, WTh, WTl, Vb);
    rope_k<<<dim3(MROWS * NHEADS / 256), blk, 0, stream>>>(Qb, Kb, pos);
    vtrans<<<dim3(BATCH * NHEADS, SEQ / 64), blk, 0, stream>>>(Vb, Vth, Vtl);
    split_x<<<dim3(NQ / 1024), blk, 0, stream>>>(Qb, Qh, Ql);
    split_x<<<dim3(NQ / 1024), blk, 0, stream>>>(Kb, Kh, Kl);
    attn_mfma<<<dim3(BATCH * NHEADS, SEQ / QB), blk, 0, stream>>>(Qh, Ql, Kh, Kl,
                                                                  Vth, Vtl, Oh, Ol);
    split_wt<<<wgrid, blk, 0, stream>>>(Wo, WTh, WTl);
    gemm_bt2<<<ggrid, blk, 0, stream>>>(Oh, Ol, WTh, WTl, (float*)d_out);
}